// Round 7
// baseline (1389.476 us; speedup 1.0000x reference)
//
#include <hip/hip_runtime.h>
#include <hip/hip_bf16.h>

typedef unsigned short u16;
typedef unsigned int u32;
#define DI __device__ __forceinline__

typedef __attribute__((ext_vector_type(8))) short v8s;
typedef __attribute__((ext_vector_type(4))) float v4f;

constexpr int B_ = 8;
constexpr int V_ = 4096;   // 64*64
constexpr int C_ = 256;    // Cin = Cout
constexpr int F_ = 128;
constexpr int E_ = 256;
constexpr int KK_ = 49;    // 7x7
constexpr int PWS = 80;    // padded row stride (u16)
constexpr int PS  = 5600;  // padded plane stride (u16), mult of 8

// ---- ws layout (float indices). Total 10,672,128 fl = 42.7 MB ----
constexpr size_t OFF_XSUM   = 0;         // 2048
constexpr size_t OFF_CSUM   = 2048;      // 2048
constexpr size_t OFF_SPHI   = 4096;      // 1024
constexpr size_t OFF_A      = 5120;      // 1024
constexpr size_t OFF_T      = 6144;      // f32 tT[b][e][f]: 262144 (atomic)
constexpr size_t OFF_TMPT   = 268288;    // f32 tmpT[b][c][e]: 524288 (atomic)
constexpr size_t ZERO_HEAD  = 792576;    // memset [0, here)
constexpr size_t OFF_TT16   = 792576;    // bf16 tT16[b][e][f]: 131072 fl
constexpr size_t OFF_T2T16  = 923648;    // bf16 tmp2T[b][c][e]: 262144 fl
constexpr size_t OFF_W2T16  = 1185792;   // bf16 w2T[co][c]: 32768 fl
constexpr size_t OFF_PHIT   = 1218560;   // bf16 phiT[b][f][v]: 2097152 fl
constexpr size_t OFF_XPT    = 3315712;   // bf16 xpadT; hmS16 overlays after gemm1
constexpr size_t XPT_FLOATS = 5734400;
constexpr size_t OFF_WMT    = 9050112;   // bf16 wmT[kk][e][c]: 1605632 fl
constexpr size_t OFF_WPT    = 10655744;  // bf16 wphiT[f][c]: 16384 fl

DI float bf2f(u16 u) {
    union { u32 i; float f; } v; v.i = ((u32)u) << 16; return v.f;
}
DI u16 f2bf(float f) {
    union { float f; u32 i; } v; v.f = f;
    u32 r = v.i + 0x7fff + ((v.i >> 16) & 1);
    return (u16)(r >> 16);
}
DI v8s pack4(u32 a, u32 b, u32 c, u32 d) {
    union { u32 u[4]; v8s v; } t; t.u[0] = a; t.u[1] = b; t.u[2] = c; t.u[3] = d;
    return t.v;
}

// ---- a[b][f] = mean(x) @ w_a + b_a ----
__global__ void k_a(const float* __restrict__ w_a, const float* __restrict__ b_a,
                    float* __restrict__ ws) {
    int b = blockIdx.x, f = threadIdx.x;
    float acc = b_a[f];
    const float* xs = &ws[OFF_XSUM + b * C_];
    for (int c = 0; c < C_; ++c)
        acc += (xs[c] * (1.0f / 4096.0f)) * w_a[c * F_ + f];
    ws[OFF_A + b * F_ + f] = acc;
}

// ---- xpadT + xsum in one x pass ----
__global__ void k_padx(const float* __restrict__ x, float* __restrict__ ws) {
    __shared__ float tile[64][68];
    int b = blockIdx.x >> 6;
    int h = blockIdx.x & 63;
    int tid = threadIdx.x;
    u16* xpt = (u16*)&ws[OFF_XPT];
    for (int cc = 0; cc < 4; ++cc) {
        int c0 = cc * 64;
        int w = tid >> 2, q = tid & 3;
        const float* xr = x + ((size_t)(b * V_ + h * 64 + w)) * C_ + c0 + q * 16;
        float4 f0 = *(const float4*)(xr);
        float4 f1 = *(const float4*)(xr + 4);
        float4 f2 = *(const float4*)(xr + 8);
        float4 f3 = *(const float4*)(xr + 12);
        __syncthreads();
        *(float4*)&tile[w][q * 16]      = f0;
        *(float4*)&tile[w][q * 16 + 4]  = f1;
        *(float4*)&tile[w][q * 16 + 8]  = f2;
        *(float4*)&tile[w][q * 16 + 12] = f3;
        __syncthreads();
        int c = tid >> 2, j4 = tid & 3;
        u16* dst = xpt + ((size_t)(b * C_ + c0 + c)) * PS + (h + 3) * PWS + 3 + j4 * 16;
        float s = 0.f;
#pragma unroll
        for (int ww = 0; ww < 16; ++ww) {
            float v = tile[j4 * 16 + ww][c];
            dst[ww] = f2bf(v);
            s += v;
        }
        atomicAdd(&ws[OFF_XSUM + b * C_ + c0 + c], s);
    }
}

// ---- wphiT[f][c] = bf16(w_phi[c][f]) ----
__global__ void k_wp(const float* __restrict__ w_phi, float* __restrict__ ws) {
    int f = blockIdx.x, c = threadIdx.x;
    ((u16*)&ws[OFF_WPT])[(size_t)f * C_ + c] = f2bf(w_phi[(size_t)c * F_ + f]);
}

// ---- wmT[kk][e][c] = bf16(w_m[kk][c][e]) ----
__global__ void k_wmt(const float* __restrict__ w_m, float* __restrict__ ws) {
    int kk = blockIdx.x;
    int e = threadIdx.x;
    u16* wmt = (u16*)&ws[OFF_WMT];
    for (int c0 = 0; c0 < C_; c0 += 8) {
        u16 pk[8];
#pragma unroll
        for (int i = 0; i < 8; ++i)
            pk[i] = f2bf(w_m[((size_t)kk * C_ + c0 + i) * E_ + e]);
        uint4 q;
        q.x = (u32)pk[0] | ((u32)pk[1] << 16);
        q.y = (u32)pk[2] | ((u32)pk[3] << 16);
        q.z = (u32)pk[4] | ((u32)pk[5] << 16);
        q.w = (u32)pk[6] | ((u32)pk[7] << 16);
        *(uint4*)(wmt + ((size_t)(kk * E_ + e)) * C_ + c0) = q;
    }
}

// ---- w2T16[co][c] = bf16(w2[c][co]) ----
__global__ void k_w2t(const float* __restrict__ w2, float* __restrict__ ws) {
    int co = blockIdx.x, c = threadIdx.x;
    ((u16*)&ws[OFF_W2T16])[(size_t)co * C_ + c] = f2bf(w2[(size_t)c * C_ + co]);
}

// ---- MFMA: phiT[b][f][v] = bf16(x @ w_phi + b_phi), sphi atomics ----
__global__ __launch_bounds__(256, 2) void k_phi2(const float* __restrict__ x,
                                                 const float* __restrict__ b_phi,
                                                 float* __restrict__ ws) {
    int b = blockIdx.x >> 5;
    int v0 = (blockIdx.x & 31) * 128;
    int tid = threadIdx.x;
    int wave = tid >> 6, lane = tid & 63, quad = lane >> 4, l15 = lane & 15;
    const u16* wpt = (const u16*)&ws[OFF_WPT];
    v4f acc[2][8];
#pragma unroll
    for (int i = 0; i < 2; ++i)
#pragma unroll
        for (int j = 0; j < 8; ++j) acc[i][j] = (v4f){0.f, 0.f, 0.f, 0.f};
#pragma unroll
    for (int kc = 0; kc < 8; ++kc) {
        v8s afr[2];
#pragma unroll
        for (int mt = 0; mt < 2; ++mt) {
            const float* ap = x + ((size_t)(b * V_ + v0 + wave * 32 + mt * 16 + l15)) * C_
                              + kc * 32 + quad * 8;
            float4 u0 = *(const float4*)(ap);
            float4 u1 = *(const float4*)(ap + 4);
            u16 pk[8] = {f2bf(u0.x), f2bf(u0.y), f2bf(u0.z), f2bf(u0.w),
                         f2bf(u1.x), f2bf(u1.y), f2bf(u1.z), f2bf(u1.w)};
            afr[mt] = pack4((u32)pk[0] | ((u32)pk[1] << 16), (u32)pk[2] | ((u32)pk[3] << 16),
                            (u32)pk[4] | ((u32)pk[5] << 16), (u32)pk[6] | ((u32)pk[7] << 16));
        }
#pragma unroll
        for (int nt = 0; nt < 8; ++nt) {
            v8s bfr = *(const v8s*)(wpt + ((size_t)(nt * 16 + l15)) * C_ + kc * 32 + quad * 8);
            acc[0][nt] = __builtin_amdgcn_mfma_f32_16x16x32_bf16(afr[0], bfr, acc[0][nt], 0, 0, 0);
            acc[1][nt] = __builtin_amdgcn_mfma_f32_16x16x32_bf16(afr[1], bfr, acc[1][nt], 0, 0, 0);
        }
    }
    u16* phiT = (u16*)&ws[OFF_PHIT];
#pragma unroll
    for (int mt = 0; mt < 2; ++mt)
#pragma unroll
        for (int nt = 0; nt < 8; ++nt) {
            int f = nt * 16 + l15;
            float bp = b_phi[f];
            u16 pk[4]; float s = 0.f;
#pragma unroll
            for (int r = 0; r < 4; ++r) {
                float val = acc[mt][nt][r] + bp;
                pk[r] = f2bf(val); s += val;
            }
            int v = v0 + wave * 32 + mt * 16 + quad * 4;
            uint2 q2;
            q2.x = (u32)pk[0] | ((u32)pk[1] << 16);
            q2.y = (u32)pk[2] | ((u32)pk[3] << 16);
            *(uint2*)(phiT + ((size_t)(b * F_ + f)) * V_ + v) = q2;
            atomicAdd(&ws[OFF_SPHI + b * F_ + f], s);
        }
}

// ---- B-fragment load with static shift KX from 8-u16-aligned base ----
template <int KX>
DI v8s loadB(const u16* p /* base + (KX & ~1) already applied */) {
    constexpr int EFF = KX & ~1;
    constexpr int M8 = EFF % 8;
    if constexpr ((KX & 1) == 0) {
        if constexpr (M8 == 0) {
            return *(const v8s*)p;
        } else if constexpr (M8 == 4) {
            uint2 a = *(const uint2*)p;
            uint2 b = *(const uint2*)(p + 4);
            return pack4(a.x, a.y, b.x, b.y);
        } else {
            const u32* q = (const u32*)p;
            return pack4(q[0], q[1], q[2], q[3]);
        }
    } else {
        u32 d[5];
        if constexpr (M8 == 0) {
            uint4 a = *(const uint4*)p;
            d[0] = a.x; d[1] = a.y; d[2] = a.z; d[3] = a.w;
            d[4] = *(const u32*)(p + 8);
        } else if constexpr (M8 == 4) {
            uint2 a = *(const uint2*)p;
            uint2 b = *(const uint2*)(p + 4);
            d[0] = a.x; d[1] = a.y; d[2] = b.x; d[3] = b.y;
            d[4] = *(const u32*)(p + 8);
        } else {
            const u32* q = (const u32*)p;
            d[0] = q[0]; d[1] = q[1]; d[2] = q[2]; d[3] = q[3]; d[4] = q[4];
        }
        return pack4((d[0] >> 16) | (d[1] << 16), (d[1] >> 16) | (d[2] << 16),
                     (d[2] >> 16) | (d[3] << 16), (d[3] >> 16) | (d[4] << 16));
    }
}

// ---- gemm1 direct-global K-loop (no LDS, no barriers) ----
template <int KX>
DI void g1_direct(const u16* __restrict__ phiT_b, const u16* __restrict__ xptb,
                  int tid, v4f acc[4][4]) {
    int wave = tid >> 6, lane = tid & 63, quad = lane >> 4, l15 = lane & 15;
    int mi2 = wave >> 2, ni2 = wave & 3;
    const u16* ab[4];
#pragma unroll
    for (int ai = 0; ai < 4; ++ai)
        ab[ai] = phiT_b + ((size_t)(mi2 * 64 + ai * 16 + l15)) * V_ + quad * 8;
    const u16* bb[4];
#pragma unroll
    for (int bi = 0; bi < 4; ++bi)
        bb[bi] = xptb + ((size_t)(ni2 * 64 + bi * 16 + l15)) * PS + quad * 8 + (KX & ~1);
#pragma unroll 2
    for (int chunk = 0; chunk < 128; ++chunk) {
        int v0 = chunk * 32;
        int boff = (chunk >> 1) * PWS + (chunk & 1) * 32;
        v8s afr[4], bfr[4];
#pragma unroll
        for (int ai = 0; ai < 4; ++ai) afr[ai] = *(const v8s*)(ab[ai] + v0);
#pragma unroll
        for (int bi = 0; bi < 4; ++bi) bfr[bi] = loadB<KX>(bb[bi] + boff);
#pragma unroll
        for (int ai = 0; ai < 4; ++ai)
#pragma unroll
            for (int bi = 0; bi < 4; ++bi)
                acc[ai][bi] = __builtin_amdgcn_mfma_f32_16x16x32_bf16(
                    afr[ai], bfr[bi], acc[ai][bi], 0, 0, 0);
    }
}

// ---- MFMA: G[b,kk][f][c] (bf16, in d_out) — direct-global operands ----
__global__ __launch_bounds__(512, 2) void k_gemm1(const float* __restrict__ ws_c,
                                                  u16* __restrict__ G) {
    int b = blockIdx.x & 7;          // XCD-swizzle: consecutive blocks = different b
    int kk = blockIdx.x >> 3;
    int ky = kk / 7, kx = kk % 7;
    int tid = threadIdx.x;
    int wave = tid >> 6, lane = tid & 63, quad = lane >> 4, l15 = lane & 15;
    int mi2 = wave >> 2, ni2 = wave & 3;
    const u16* phiT_b = (const u16*)&ws_c[OFF_PHIT] + (size_t)b * F_ * V_;
    const u16* xptb   = (const u16*)&ws_c[OFF_XPT] + (size_t)b * C_ * PS + ky * PWS;
    v4f acc[4][4];
#pragma unroll
    for (int i = 0; i < 4; ++i)
#pragma unroll
        for (int j = 0; j < 4; ++j) acc[i][j] = (v4f){0.f, 0.f, 0.f, 0.f};
    switch (kx) {
        case 0: g1_direct<0>(phiT_b, xptb, tid, acc); break;
        case 1: g1_direct<1>(phiT_b, xptb, tid, acc); break;
        case 2: g1_direct<2>(phiT_b, xptb, tid, acc); break;
        case 3: g1_direct<3>(phiT_b, xptb, tid, acc); break;
        case 4: g1_direct<4>(phiT_b, xptb, tid, acc); break;
        case 5: g1_direct<5>(phiT_b, xptb, tid, acc); break;
        case 6: g1_direct<6>(phiT_b, xptb, tid, acc); break;
    }
    u16* Gb = G + ((size_t)(b * KK_ + kk)) * F_ * C_;
#pragma unroll
    for (int ai = 0; ai < 4; ++ai)
#pragma unroll
        for (int bi = 0; bi < 4; ++bi) {
            int c = ni2 * 64 + bi * 16 + l15;
#pragma unroll
            for (int r = 0; r < 4; ++r) {
                int f = mi2 * 64 + ai * 16 + quad * 4 + r;
                Gb[(size_t)f * C_ + c] = f2bf(acc[ai][bi][r]);
            }
        }
}

// ---- MFMA: tT[b][e][f] += G @ wmT (atomic f32) ----
__global__ void k_gemm2(const u16* __restrict__ G, float* __restrict__ ws) {
    int blk = blockIdx.x;
    int kg = blk % 7; blk /= 7;
    int ei = blk % 4; blk /= 4;
    int fi = blk % 2; int b = blk / 2;
    int tid = threadIdx.x;
    int wave = tid >> 6, lane = tid & 63, quad = lane >> 4, l15 = lane & 15;
    int fbase = fi * 64 + wave * 16;
    int ebase = ei * 64;
    const u16* wmt = (const u16*)&ws[OFF_WMT];
    const u16* Gb = G + (size_t)b * KK_ * F_ * C_;
    v4f acc[4];
#pragma unroll
    for (int i = 0; i < 4; ++i) acc[i] = (v4f){0.f, 0.f, 0.f, 0.f};
    for (int kk = kg * 7; kk < kg * 7 + 7; ++kk) {
        const u16* Ga = Gb + ((size_t)kk * F_ + fbase + l15) * C_;
        const u16* Wb = wmt + ((size_t)kk * E_ + ebase + l15) * C_;
#pragma unroll 2
        for (int cs = 0; cs < 8; ++cs) {
            v8s af = *(const v8s*)(Ga + cs * 32 + quad * 8);
#pragma unroll
            for (int nt = 0; nt < 4; ++nt) {
                v8s bf = *(const v8s*)(Wb + (size_t)nt * 16 * C_ + cs * 32 + quad * 8);
                acc[nt] = __builtin_amdgcn_mfma_f32_16x16x32_bf16(af, bf, acc[nt], 0, 0, 0);
            }
        }
    }
#pragma unroll
    for (int nt = 0; nt < 4; ++nt)
#pragma unroll
        for (int r = 0; r < 4; ++r) {
            int e = ebase + nt * 16 + l15;
            int f = fbase + quad * 4 + r;
            atomicAdd(&ws[OFF_T + ((size_t)(b * E_ + e)) * F_ + f], acc[nt][r]);
        }
}

// ---- tT16[b][e][f] = bf16( a[b,f] * (tT + sphi[b,f]*b_m[e]) ) ----
__global__ void k_tfix(const float* __restrict__ b_m, float* __restrict__ ws) {
    int b = blockIdx.x >> 8, e = blockIdx.x & 255, f = threadIdx.x;
    float av = ws[OFF_A + b * F_ + f];
    float sp = ws[OFF_SPHI + b * F_ + f];
    float t = av * (ws[OFF_T + ((size_t)(b * E_ + e)) * F_ + f] + sp * b_m[e]);
    ((u16*)&ws[OFF_TT16])[((size_t)(b * E_ + e)) * F_ + f] = f2bf(t);
}

// ---- MFMA: hmS16[v][e] = bf16(rsD[v]*|phi@t|), csum atomic ----
__global__ void k_hd(float* __restrict__ ws) {
    __shared__ u16 phiL[64 * 136];
    int b = blockIdx.x >> 6;
    int v0 = (blockIdx.x & 63) * 64;
    int tid = threadIdx.x;
    {
        int f = tid & 127, seg = (tid >> 7) * 32;
        const u16* src = (const u16*)&ws[OFF_PHIT] + ((size_t)(b * F_ + f)) * V_ + v0 + seg;
        uint4 q0 = *(const uint4*)(src);
        uint4 q1 = *(const uint4*)(src + 8);
        uint4 q2 = *(const uint4*)(src + 16);
        uint4 q3 = *(const uint4*)(src + 24);
        u32 dw[16] = {q0.x, q0.y, q0.z, q0.w, q1.x, q1.y, q1.z, q1.w,
                      q2.x, q2.y, q2.z, q2.w, q3.x, q3.y, q3.z, q3.w};
#pragma unroll
        for (int j = 0; j < 16; ++j) {
            phiL[(seg + 2 * j) * 136 + f]     = (u16)(dw[j] & 0xffff);
            phiL[(seg + 2 * j + 1) * 136 + f] = (u16)(dw[j] >> 16);
        }
    }
    __syncthreads();
    int wave = tid >> 6, lane = tid & 63, quad = lane >> 4, l15 = lane & 15;
    const u16* tt = (const u16*)&ws[OFF_TT16] + (size_t)b * E_ * F_;
    v4f acc[16];
#pragma unroll
    for (int i = 0; i < 16; ++i) acc[i] = (v4f){0.f, 0.f, 0.f, 0.f};
#pragma unroll
    for (int kc = 0; kc < 4; ++kc) {
        v8s af = *(const v8s*)&phiL[(wave * 16 + l15) * 136 + kc * 32 + quad * 8];
#pragma unroll
        for (int nt = 0; nt < 16; ++nt) {
            v8s bf = *(const v8s*)(tt + (size_t)(nt * 16 + l15) * F_ + kc * 32 + quad * 8);
            acc[nt] = __builtin_amdgcn_mfma_f32_16x16x32_bf16(af, bf, acc[nt], 0, 0, 0);
        }
    }
#pragma unroll
    for (int nt = 0; nt < 16; ++nt)
#pragma unroll
        for (int r = 0; r < 4; ++r) acc[nt][r] = fabsf(acc[nt][r]);
    v4f rs = acc[0];
#pragma unroll
    for (int nt = 1; nt < 16; ++nt) rs += acc[nt];
#pragma unroll
    for (int m = 1; m < 16; m <<= 1) {
#pragma unroll
        for (int r = 0; r < 4; ++r) rs[r] += __shfl_xor(rs[r], m, 64);
    }
    float rsd[4];
#pragma unroll
    for (int r = 0; r < 4; ++r) rsd[r] = rsqrtf(rs[r]);
#pragma unroll
    for (int nt = 0; nt < 16; ++nt) {
        float cs = acc[nt][0] + acc[nt][1] + acc[nt][2] + acc[nt][3];
        atomicAdd(&ws[OFF_CSUM + b * E_ + nt * 16 + l15], cs);
    }
    u16* hm = (u16*)&ws[OFF_XPT];
#pragma unroll
    for (int nt = 0; nt < 16; ++nt)
#pragma unroll
        for (int r = 0; r < 4; ++r) {
            int v = v0 + wave * 16 + quad * 4 + r;
            hm[((size_t)(b * V_ + v)) * E_ + nt * 16 + l15] = f2bf(acc[nt][r] * rsd[r]);
        }
}

// ---- MFMA: tmpT[b][c][e] += sum_v xT[c][v]*hmS^T[e][v] (atomic f32) ----
__global__ __launch_bounds__(512, 2) void k_tmp(const float* __restrict__ x,
                                                float* __restrict__ ws) {
    __shared__ u16 xT[256 * 40];
    __shared__ u16 hT[128 * 40];
    int blk = blockIdx.x;
    int eh = blk & 1; blk >>= 1;
    int vs = blk & 15; int b = blk >> 4;
    int v0b = vs * 256;
    int tid = threadIdx.x;
    int wave = tid >> 6, lane = tid & 63, quad = lane >> 4, l15 = lane & 15;
    int m0 = wave * 32;
    const u16* hmS = (const u16*)&ws[OFF_XPT];
    v4f acc[2][8];
#pragma unroll
    for (int i = 0; i < 2; ++i)
#pragma unroll
        for (int j = 0; j < 8; ++j) acc[i][j] = (v4f){0.f, 0.f, 0.f, 0.f};
    int sv = tid & 31, sg = tid >> 5;
#pragma unroll 1
    for (int ch = 0; ch < 8; ++ch) {
        int vbase = v0b + ch * 32;
        const float* xr = x + ((size_t)(b * V_ + vbase + sv)) * C_ + sg * 16;
        float4 xf0 = *(const float4*)(xr);
        float4 xf1 = *(const float4*)(xr + 4);
        float4 xf2 = *(const float4*)(xr + 8);
        float4 xf3 = *(const float4*)(xr + 12);
        const u16* hr = hmS + ((size_t)(b * V_ + vbase + sv)) * E_ + eh * 128 + sg * 8;
        uint4 hq = *(const uint4*)hr;
        u16 hp[8] = {(u16)(hq.x & 0xffff), (u16)(hq.x >> 16), (u16)(hq.y & 0xffff),
                     (u16)(hq.y >> 16), (u16)(hq.z & 0xffff), (u16)(hq.z >> 16),
                     (u16)(hq.w & 0xffff), (u16)(hq.w >> 16)};
        float xv[16] = {xf0.x, xf0.y, xf0.z, xf0.w, xf1.x, xf1.y, xf1.z, xf1.w,
                        xf2.x, xf2.y, xf2.z, xf2.w, xf3.x, xf3.y, xf3.z, xf3.w};
        __syncthreads();
#pragma unroll
        for (int i = 0; i < 16; ++i) xT[(sg * 16 + i) * 40 + sv] = f2bf(xv[i]);
#pragma unroll
        for (int i = 0; i < 8; ++i) hT[(sg * 8 + i) * 40 + sv] = hp[i];
        __syncthreads();
        v8s a0 = *(const v8s*)&xT[(m0 + l15) * 40 + quad * 8];
        v8s a1 = *(const v8s*)&xT[(m0 + 16 + l15) * 40 + quad * 8];
#pragma unroll
        for (int nt = 0; nt < 8; ++nt) {
            v8s bf = *(const v8s*)&hT[(nt * 16 + l15) * 40 + quad * 8];
            acc[0][nt] = __builtin_amdgcn_mfma_f32_16x16x32_bf16(a0, bf, acc[0][nt], 0, 0, 0);
            acc[1][nt] = __builtin_amdgcn_mfma_f32_16x16x32_bf16(a1, bf, acc[1][nt], 0, 0, 0);
        }
    }
#pragma unroll
    for (int mt = 0; mt < 2; ++mt)
#pragma unroll
        for (int nt = 0; nt < 8; ++nt)
#pragma unroll
            for (int r = 0; r < 4; ++r) {
                int c = m0 + mt * 16 + quad * 4 + r;
                int e = eh * 128 + nt * 16 + l15;
                atomicAdd(&ws[OFF_TMPT + ((size_t)(b * C_ + c)) * E_ + e], acc[mt][nt][r]);
            }
}

// ---- tmp2T16[c][e] = bf16(tmpT[c][e] / csum[e]) ----
__global__ void k_t2fix(float* __restrict__ ws) {
    int b = blockIdx.x >> 8, c = blockIdx.x & 255, e = threadIdx.x;
    float binv = 1.0f / ws[OFF_CSUM + b * E_ + e];
    float tv = ws[OFF_TMPT + ((size_t)(b * C_ + c)) * E_ + e];
    ((u16*)&ws[OFF_T2T16])[((size_t)(b * C_ + c)) * E_ + e] = f2bf(tv * binv);
}

// ---- MFMA fused: out = (x - hmS16 @ tmp2T16) @ W2 + b2 ----
__global__ __launch_bounds__(256, 2) void k_out(const float* __restrict__ x,
                                                const float* __restrict__ b2,
                                                const float* __restrict__ ws,
                                                float* __restrict__ io) {
    __shared__ u16 dL[64 * 264];
    int b = blockIdx.x >> 6;
    int v0 = (blockIdx.x & 63) * 64;
    int tid = threadIdx.x;
    int wave = tid >> 6, lane = tid & 63, quad = lane >> 4, l15 = lane & 15;
    const u16* hm = (const u16*)&ws[OFF_XPT] + ((size_t)(b * V_ + v0 + wave * 16 + l15)) * E_;
    const u16* t2 = (const u16*)&ws[OFF_T2T16] + (size_t)b * C_ * E_;
    v4f acc[16];
#pragma unroll
    for (int i = 0; i < 16; ++i) acc[i] = (v4f){0.f, 0.f, 0.f, 0.f};
#pragma unroll 2
    for (int kc = 0; kc < 8; ++kc) {
        v8s af = *(const v8s*)(hm + kc * 32 + quad * 8);
#pragma unroll
        for (int nt = 0; nt < 16; ++nt) {
            v8s bf = *(const v8s*)(t2 + (size_t)(nt * 16 + l15) * E_ + kc * 32 + quad * 8);
            acc[nt] = __builtin_amdgcn_mfma_f32_16x16x32_bf16(af, bf, acc[nt], 0, 0, 0);
        }
    }
#pragma unroll
    for (int nt = 0; nt < 16; ++nt)
#pragma unroll
        for (int r = 0; r < 4; ++r) {
            int v = wave * 16 + quad * 4 + r;
            int c = nt * 16 + l15;
            float xv = x[((size_t)(b * V_ + v0 + v)) * C_ + c];
            dL[v * 264 + c] = f2bf(xv - acc[nt][r]);
        }
    __syncthreads();
    const u16* w2t = (const u16*)&ws[OFF_W2T16];
    v4f acc2[16];
#pragma unroll
    for (int i = 0; i < 16; ++i) acc2[i] = (v4f){0.f, 0.f, 0.f, 0.f};
#pragma unroll 2
    for (int kc = 0; kc < 8; ++kc) {
        v8s af = *(const v8s*)&dL[(wave * 16 + l15) * 264 + kc * 32 + quad * 8];
#pragma unroll
        for (int nt = 0; nt < 16; ++nt) {
            v8s bf = *(const v8s*)(w2t + (size_t)(nt * 16 + l15) * C_ + kc * 32 + quad * 8);
            acc2[nt] = __builtin_amdgcn_mfma_f32_16x16x32_bf16(af, bf, acc2[nt], 0, 0, 0);
        }
    }
#pragma unroll
    for (int nt = 0; nt < 16; ++nt)
#pragma unroll
        for (int r = 0; r < 4; ++r) {
            int v = wave * 16 + quad * 4 + r;
            int co = nt * 16 + l15;
            io[((size_t)(b * V_ + v0 + v)) * C_ + co] = acc2[nt][r] + b2[co];
        }
}

extern "C" void kernel_launch(void* const* d_in, const int* in_sizes, int n_in,
                              void* d_out, int out_size, void* d_ws, size_t ws_size,
                              hipStream_t stream) {
    const float* x     = (const float*)d_in[0];
    const float* w_phi = (const float*)d_in[1];
    const float* b_phi = (const float*)d_in[2];
    const float* w_a   = (const float*)d_in[3];
    const float* b_a   = (const float*)d_in[4];
    const float* w_m   = (const float*)d_in[5];
    const float* b_m   = (const float*)d_in[6];
    const float* w2    = (const float*)d_in[7];
    const float* b2    = (const float*)d_in[8];
    float* ws = (float*)d_ws;
    float* io = (float*)d_out;

    hipMemsetAsync(ws, 0, ZERO_HEAD * sizeof(float), stream);
    hipMemsetAsync(ws + OFF_XPT, 0, XPT_FLOATS * sizeof(float), stream);
    k_padx<<<dim3(512), dim3(256), 0, stream>>>(x, ws);
    k_a<<<dim3(8), dim3(128), 0, stream>>>(w_a, b_a, ws);
    k_wp<<<dim3(128), dim3(256), 0, stream>>>(w_phi, ws);
    k_phi2<<<dim3(256), dim3(256), 0, stream>>>(x, b_phi, ws);
    k_wmt<<<dim3(49), dim3(256), 0, stream>>>(w_m, ws);
    k_w2t<<<dim3(256), dim3(256), 0, stream>>>(w2, ws);
    k_gemm1<<<dim3(392), dim3(512), 0, stream>>>(ws, (u16*)d_out);
    k_gemm2<<<dim3(448), dim3(256), 0, stream>>>((const u16*)d_out, ws);
    k_tfix<<<dim3(2048), dim3(128), 0, stream>>>(b_m, ws);
    k_hd<<<dim3(512), dim3(256), 0, stream>>>(ws);
    k_tmp<<<dim3(256), dim3(512), 0, stream>>>(x, ws);
    k_t2fix<<<dim3(2048), dim3(256), 0, stream>>>(ws);
    k_out<<<dim3(512), dim3(256), 0, stream>>>(x, b2, ws, io);
}